// Round 1
// baseline (6996.089 us; speedup 1.0000x reference)
//
#include <hip/hip_runtime.h>

#define HH 720
#define WW 1280
#define HWP (HH*WW)

static constexpr int NFRM = 4;

// ---------------- LCN: rec_in = [lcn(color), color]  (6 planes) ----------------
__global__ __launch_bounds__(256) void lcn_kernel(const float* __restrict__ color,
                                                  float* __restrict__ out) {
  int p = blockIdx.x * blockDim.x + threadIdx.x;
  if (p >= HWP) return;
  int y = p / WW, x = p - y * WW;
  #pragma unroll
  for (int c = 0; c < 3; ++c) {
    const float* ch = color + c * HWP;
    float s = 0.f, s2 = 0.f;
    #pragma unroll
    for (int dy = -1; dy <= 1; ++dy) {
      int iy = y + dy;
      if (iy < 0 || iy >= HH) continue;
      #pragma unroll
      for (int dx = -1; dx <= 1; ++dx) {
        int ix = x + dx;
        if (ix < 0 || ix >= WW) continue;
        float v = ch[iy * WW + ix];
        s += v; s2 = fmaf(v, v, s2);
      }
    }
    float mean = s * (1.f / 9.f);
    float mean2 = s2 * (1.f / 9.f);
    float var = fmaxf(mean2 - mean * mean, 0.f);
    float cv = ch[p];
    out[c * HWP + p] = (cv - mean) * rsqrtf(var + 1e-5f);
    out[(3 + c) * HWP + p] = cv;
  }
}

// ---------------- generic 3x3 SAME conv, split input [in0:C0][in1:C1] ----------------
template <int C0, int C1, int COUT, bool RELU>
__global__ __launch_bounds__(256) void conv3x3_k(const float* __restrict__ in0,
                                                 const float* __restrict__ in1,
                                                 const float* __restrict__ w,
                                                 const float* __restrict__ b,
                                                 float* __restrict__ out) {
  int p = blockIdx.x * blockDim.x + threadIdx.x;
  if (p >= HWP) return;
  int y = p / WW, x = p - y * WW;
  constexpr int CIN = C0 + C1;
  float acc[COUT];
  #pragma unroll
  for (int co = 0; co < COUT; ++co) acc[co] = b[co];
  #pragma unroll
  for (int ky = 0; ky < 3; ++ky) {
    int iy = y + ky - 1;
    bool yok = (iy >= 0) && (iy < HH);
    #pragma unroll
    for (int kx = 0; kx < 3; ++kx) {
      int ix = x + kx - 1;
      bool ok = yok && (ix >= 0) && (ix < WW);
      int off = iy * WW + ix;
      #pragma unroll
      for (int c = 0; c < C0; ++c) {
        float v = ok ? in0[c * HWP + off] : 0.f;
        #pragma unroll
        for (int co = 0; co < COUT; ++co)
          acc[co] = fmaf(w[((co * CIN + c) * 3 + ky) * 3 + kx], v, acc[co]);
      }
      #pragma unroll
      for (int c = 0; c < C1; ++c) {
        float v = ok ? in1[c * HWP + off] : 0.f;
        #pragma unroll
        for (int co = 0; co < COUT; ++co)
          acc[co] = fmaf(w[((co * CIN + C0 + c) * 3 + ky) * 3 + kx], v, acc[co]);
      }
    }
  }
  #pragma unroll
  for (int co = 0; co < COUT; ++co) {
    float v = RELU ? fmaxf(acc[co], 0.f) : acc[co];
    out[co * HWP + p] = v;
  }
}

// ---------------- temporal blend: dyn[0..2]=color (blended), dyn[3] blended in place ----------------
__global__ __launch_bounds__(256) void blend_kernel(const float* __restrict__ color,
                                                    const float* __restrict__ temporal,
                                                    const float* __restrict__ alpha,
                                                    float* __restrict__ dyn, int first) {
  int p = blockIdx.x * blockDim.x + threadIdx.x;
  if (p >= HWP) return;
  if (first) {
    #pragma unroll
    for (int c = 0; c < 3; ++c) dyn[c * HWP + p] = color[c * HWP + p];
  } else {
    float a = alpha[0];
    float om = 1.f - a;
    #pragma unroll
    for (int c = 0; c < 3; ++c)
      dyn[c * HWP + p] = a * color[c * HWP + p] + om * temporal[c * HWP + p];
    dyn[3 * HWP + p] = a * dyn[3 * HWP + p] + om * temporal[3 * HWP + p];
  }
}

// ---------------- bilateral 7x7, edge-clamped; LDS tile [22][22][12] ----------------
#define TS 16
#define HALO 3
#define TL (TS + 2 * HALO)   // 22
#define NCH 12               // 4 dyn + 8 feat, channel-contiguous per pixel

__global__ __launch_bounds__(256) void bilateral_kernel(const float* __restrict__ dyn,
                                                        const float* __restrict__ feat,
                                                        const float* __restrict__ scale,
                                                        float* __restrict__ outdyn) {
  __shared__ float tile[TL * TL * NCH];
  constexpr int NBX = WW / TS;  // 80
  int bx = blockIdx.x % NBX;
  int by = blockIdx.x / NBX;
  int tx = threadIdx.x % TS;
  int ty = threadIdx.x / TS;

  // cooperative load, channel-major for coalesced global reads
  for (int idx = threadIdx.x; idx < NCH * TL * TL; idx += 256) {
    int c = idx / (TL * TL);
    int rem = idx - c * (TL * TL);
    int ly = rem / TL;
    int lx = rem - ly * TL;
    int gy = min(max(by * TS + ly - HALO, 0), HH - 1);
    int gx = min(max(bx * TS + lx - HALO, 0), WW - 1);
    float v = (c < 4) ? dyn[c * HWP + gy * WW + gx]
                      : feat[(c - 4) * HWP + gy * WW + gx];
    tile[(ly * TL + lx) * NCH + c] = v;
  }
  __syncthreads();

  float s[8];
  #pragma unroll
  for (int c = 0; c < 8; ++c) s[c] = scale[c];

  const float* center = &tile[((ty + HALO) * TL + (tx + HALO)) * NCH];
  float fc[8];
  #pragma unroll
  for (int c = 0; c < 8; ++c) fc[c] = center[4 + c];

  float acc0 = 0.f, acc1 = 0.f, acc2 = 0.f, acc3 = 0.f, wsum = 0.f;
  #pragma unroll
  for (int dy = 0; dy < 7; ++dy) {
    #pragma unroll
    for (int dx = 0; dx < 7; ++dx) {
      const float* q = &tile[((ty + dy) * TL + (tx + dx)) * NCH];
      float4 f0 = *reinterpret_cast<const float4*>(q + 4);
      float4 f1 = *reinterpret_cast<const float4*>(q + 8);
      float e = 0.f;
      float d;
      d = fc[0] - f0.x; e = fmaf(s[0] * d, d, e);
      d = fc[1] - f0.y; e = fmaf(s[1] * d, d, e);
      d = fc[2] - f0.z; e = fmaf(s[2] * d, d, e);
      d = fc[3] - f0.w; e = fmaf(s[3] * d, d, e);
      d = fc[4] - f1.x; e = fmaf(s[4] * d, d, e);
      d = fc[5] - f1.y; e = fmaf(s[5] * d, d, e);
      d = fc[6] - f1.z; e = fmaf(s[6] * d, d, e);
      d = fc[7] - f1.w; e = fmaf(s[7] * d, d, e);
      float wgt = __expf(-e);
      float4 dv = *reinterpret_cast<const float4*>(q);
      acc0 = fmaf(wgt, dv.x, acc0);
      acc1 = fmaf(wgt, dv.y, acc1);
      acc2 = fmaf(wgt, dv.z, acc2);
      acc3 = fmaf(wgt, dv.w, acc3);
      wsum += wgt;
    }
  }
  int gy = by * TS + ty, gx = bx * TS + tx;
  int p = gy * WW + gx;
  float inv = 1.f / (wsum + 1e-8f);
  outdyn[0 * HWP + p] = acc0 * inv;
  outdyn[1 * HWP + p] = acc1 * inv;
  outdyn[2 * HWP + p] = acc2 * inv;
  outdyn[3 * HWP + p] = acc3 * inv;
}

// ---------------- output: albedo * dyn[0..2] ----------------
__global__ __launch_bounds__(256) void out_kernel(const float* __restrict__ albedo,
                                                  const float* __restrict__ dyn,
                                                  float* __restrict__ out) {
  int p = blockIdx.x * blockDim.x + threadIdx.x;
  if (p >= HWP) return;
  #pragma unroll
  for (int c = 0; c < 3; ++c)
    out[c * HWP + p] = albedo[c * HWP + p] * dyn[c * HWP + p];
}

extern "C" void kernel_launch(void* const* d_in, const int* in_sizes, int n_in,
                              void* d_out, int out_size, void* d_ws, size_t ws_size,
                              hipStream_t stream) {
  const float* x          = (const float*)d_in[0];
  const float* alpha      = (const float*)d_in[1];
  const float* cr_w0      = (const float*)d_in[2];
  const float* cr_b0      = (const float*)d_in[3];
  const float* cr_w1      = (const float*)d_in[4];
  const float* cr_b1      = (const float*)d_in[5];
  const float* cr_w2      = (const float*)d_in[6];
  const float* cr_b2      = (const float*)d_in[7];
  const float* hs_w0      = (const float*)d_in[8];
  const float* hs_b0      = (const float*)d_in[9];
  const float* hs_w1      = (const float*)d_in[10];
  const float* hs_b1      = (const float*)d_in[11];
  const float* hs_w2      = (const float*)d_in[12];
  const float* hs_b2      = (const float*)d_in[13];
  const float* filt_w     = (const float*)d_in[14];
  const float* filt_b     = (const float*)d_in[15];
  const float* filt_scale = (const float*)d_in[16];

  float* out  = (float*)d_out;
  float* ws   = (float*)d_ws;
  float* buf0 = ws;               // 12 planes
  float* buf1 = ws + 12 * HWP;    // 12 planes
  float* dynA = ws + 24 * HWP;    // 4 planes
  float* dynB = ws + 28 * HWP;    // 4 planes
  float* feat = buf0;             // 8 planes, aliases buf0 (free during filter loop)

  const int NB = HWP / 256;       // 3600 blocks
  dim3 blk(256);

  for (int i = 0; i < NFRM; ++i) {
    const float* frame  = x + (size_t)i * 12 * HWP;
    const float* color  = frame;
    const float* fixedp = frame + 3 * HWP;  // 9 planes (includes albedo at 0..2)
    const float* albedo = frame + 3 * HWP;

    lcn_kernel<<<NB, blk, 0, stream>>>(color, buf0);
    conv3x3_k<6, 0, 6, true><<<NB, blk, 0, stream>>>(buf0, nullptr, cr_w0, cr_b0, buf1);
    conv3x3_k<6, 0, 12, true><<<NB, blk, 0, stream>>>(buf1, nullptr, cr_w1, cr_b1, buf0);
    conv3x3_k<12, 0, 3, false><<<NB, blk, 0, stream>>>(buf0, nullptr, cr_w2, cr_b2, buf1);
    conv3x3_k<3, 9, 12, true><<<NB, blk, 0, stream>>>(buf1, fixedp, hs_w0, hs_b0, buf0);
    conv3x3_k<12, 0, 12, true><<<NB, blk, 0, stream>>>(buf0, nullptr, hs_w1, hs_b1, buf1);
    conv3x3_k<12, 0, 1, false><<<NB, blk, 0, stream>>>(buf1, nullptr, hs_w2, hs_b2, dynA + 3 * HWP);
    blend_kernel<<<NB, blk, 0, stream>>>(color, dynB, alpha, dynA, i == 0 ? 1 : 0);

    float* cur = dynA;
    float* nxt = dynB;
    for (int k = 0; k < 5; ++k) {
      conv3x3_k<4, 9, 8, false><<<NB, blk, 0, stream>>>(cur, fixedp,
                                                        filt_w + (size_t)k * 8 * 13 * 9,
                                                        filt_b + k * 8, feat);
      bilateral_kernel<<<NB, blk, 0, stream>>>(cur, feat, filt_scale + k * 8, nxt);
      float* t = cur; cur = nxt; nxt = t;
    }
    // cur == dynB here (5 swaps); dynB is the temporal state read next frame
    out_kernel<<<NB, blk, 0, stream>>>(albedo, cur, out + (size_t)i * 3 * HWP);
  }
}

// Round 2
// 3378.163 us; speedup vs baseline: 2.0710x; 2.0710x over previous
//
#include <hip/hip_runtime.h>

#define HH 720
#define WW 1280
#define HWP (HH*WW)

static constexpr int NFRM = 4;

// ================= register-tiled 3x3 SAME conv: 8 px/thread =================
// block = 128 threads = (16 x-threads) x (8 y); tile 128x8; grid = 10*90 = 900
template <int C0, int C1, int COUT, bool RELU>
__global__ __launch_bounds__(128) void conv3x3_v2(const float* __restrict__ in0,
                                                  const float* __restrict__ in1,
                                                  const float* __restrict__ w,
                                                  const float* __restrict__ b,
                                                  float* __restrict__ out) {
  constexpr int CIN = C0 + C1;
  constexpr int NBX = WW / 128;  // 10
  int bx = blockIdx.x % NBX;
  int by = blockIdx.x / NBX;     // 0..89
  int tx = threadIdx.x & 15;
  int ty = threadIdx.x >> 4;     // 0..7
  int gx0 = bx * 128 + tx * 8;
  int gy  = by * 8 + ty;

  float acc[COUT][8];
  #pragma unroll
  for (int co = 0; co < COUT; ++co) {
    float bv = b[co];
    #pragma unroll
    for (int px = 0; px < 8; ++px) acc[co][px] = bv;
  }

  const bool lok = (gx0 > 0);
  const bool rok = (gx0 + 8 < WW);

  for (int c = 0; c < CIN; ++c) {
    const float* ch = (c < C0) ? (in0 + (size_t)c * HWP)
                               : (in1 + (size_t)(c - C0) * HWP);
    float r[3][10];
    #pragma unroll
    for (int ky = 0; ky < 3; ++ky) {
      int iy = gy + ky - 1;
      bool yok = (iy >= 0) && (iy < HH);
      const float* row = ch + (ptrdiff_t)iy * WW;
      float4 a = yok ? *reinterpret_cast<const float4*>(row + gx0)
                     : make_float4(0.f, 0.f, 0.f, 0.f);
      float4 q = yok ? *reinterpret_cast<const float4*>(row + gx0 + 4)
                     : make_float4(0.f, 0.f, 0.f, 0.f);
      r[ky][0] = (yok && lok) ? row[gx0 - 1] : 0.f;
      r[ky][1] = a.x; r[ky][2] = a.y; r[ky][3] = a.z; r[ky][4] = a.w;
      r[ky][5] = q.x; r[ky][6] = q.y; r[ky][7] = q.z; r[ky][8] = q.w;
      r[ky][9] = (yok && rok) ? row[gx0 + 8] : 0.f;
    }
    #pragma unroll
    for (int co = 0; co < COUT; ++co) {
      #pragma unroll
      for (int ky = 0; ky < 3; ++ky) {
        #pragma unroll
        for (int kx = 0; kx < 3; ++kx) {
          float wv = w[((co * CIN + c) * 3 + ky) * 3 + kx];
          #pragma unroll
          for (int px = 0; px < 8; ++px)
            acc[co][px] = fmaf(wv, r[ky][px + kx], acc[co][px]);
        }
      }
    }
  }

  size_t p = (size_t)gy * WW + gx0;
  #pragma unroll
  for (int co = 0; co < COUT; ++co) {
    float4 o0, o1;
    o0.x = RELU ? fmaxf(acc[co][0], 0.f) : acc[co][0];
    o0.y = RELU ? fmaxf(acc[co][1], 0.f) : acc[co][1];
    o0.z = RELU ? fmaxf(acc[co][2], 0.f) : acc[co][2];
    o0.w = RELU ? fmaxf(acc[co][3], 0.f) : acc[co][3];
    o1.x = RELU ? fmaxf(acc[co][4], 0.f) : acc[co][4];
    o1.y = RELU ? fmaxf(acc[co][5], 0.f) : acc[co][5];
    o1.z = RELU ? fmaxf(acc[co][6], 0.f) : acc[co][6];
    o1.w = RELU ? fmaxf(acc[co][7], 0.f) : acc[co][7];
    *reinterpret_cast<float4*>(out + (size_t)co * HWP + p) = o0;
    *reinterpret_cast<float4*>(out + (size_t)co * HWP + p + 4) = o1;
  }
}

// ================= LCN: out = [lcn(color), color] (6 planes), 8 px/thread =================
__global__ __launch_bounds__(128) void lcn_v2(const float* __restrict__ color,
                                              float* __restrict__ out) {
  constexpr int NBX = WW / 128;
  int bx = blockIdx.x % NBX;
  int by = blockIdx.x / NBX;
  int tx = threadIdx.x & 15;
  int ty = threadIdx.x >> 4;
  int gx0 = bx * 128 + tx * 8;
  int gy  = by * 8 + ty;
  const bool lok = (gx0 > 0);
  const bool rok = (gx0 + 8 < WW);
  size_t p = (size_t)gy * WW + gx0;

  #pragma unroll
  for (int c = 0; c < 3; ++c) {
    const float* ch = color + (size_t)c * HWP;
    float r[3][10];
    #pragma unroll
    for (int ky = 0; ky < 3; ++ky) {
      int iy = gy + ky - 1;
      bool yok = (iy >= 0) && (iy < HH);
      const float* row = ch + (ptrdiff_t)iy * WW;
      float4 a = yok ? *reinterpret_cast<const float4*>(row + gx0)
                     : make_float4(0.f, 0.f, 0.f, 0.f);
      float4 q = yok ? *reinterpret_cast<const float4*>(row + gx0 + 4)
                     : make_float4(0.f, 0.f, 0.f, 0.f);
      r[ky][0] = (yok && lok) ? row[gx0 - 1] : 0.f;
      r[ky][1] = a.x; r[ky][2] = a.y; r[ky][3] = a.z; r[ky][4] = a.w;
      r[ky][5] = q.x; r[ky][6] = q.y; r[ky][7] = q.z; r[ky][8] = q.w;
      r[ky][9] = (yok && rok) ? row[gx0 + 8] : 0.f;
    }
    float lcnv[8], cv[8];
    #pragma unroll
    for (int px = 0; px < 8; ++px) {
      float s = 0.f, s2 = 0.f;
      #pragma unroll
      for (int ky = 0; ky < 3; ++ky)
        #pragma unroll
        for (int kx = 0; kx < 3; ++kx) {
          float v = r[ky][px + kx];
          s += v; s2 = fmaf(v, v, s2);
        }
      float mean = s * (1.f / 9.f);
      float mean2 = s2 * (1.f / 9.f);
      float var = fmaxf(mean2 - mean * mean, 0.f);
      cv[px] = r[1][px + 1];
      lcnv[px] = (cv[px] - mean) * rsqrtf(var + 1e-5f);
    }
    #pragma unroll
    for (int h = 0; h < 2; ++h) {
      float4 o0 = make_float4(lcnv[4*h+0], lcnv[4*h+1], lcnv[4*h+2], lcnv[4*h+3]);
      float4 o1 = make_float4(cv[4*h+0], cv[4*h+1], cv[4*h+2], cv[4*h+3]);
      *reinterpret_cast<float4*>(out + (size_t)c * HWP + p + 4*h) = o0;
      *reinterpret_cast<float4*>(out + (size_t)(3 + c) * HWP + p + 4*h) = o1;
    }
  }
}

// ================= temporal blend, float4 x 4px =================
__global__ __launch_bounds__(256) void blend_v2(const float* __restrict__ color,
                                                const float* __restrict__ temporal,
                                                const float* __restrict__ alpha,
                                                float* __restrict__ dyn, int first) {
  int i = (blockIdx.x * 256 + threadIdx.x) * 4;
  if (i >= HWP) return;
  if (first) {
    #pragma unroll
    for (int c = 0; c < 3; ++c)
      *reinterpret_cast<float4*>(dyn + (size_t)c * HWP + i) =
          *reinterpret_cast<const float4*>(color + (size_t)c * HWP + i);
  } else {
    float a = alpha[0];
    float om = 1.f - a;
    #pragma unroll
    for (int c = 0; c < 4; ++c) {
      const float* src = (c < 3) ? (color + (size_t)c * HWP) : (dyn + 3 * (size_t)HWP);
      float4 cv = *reinterpret_cast<const float4*>(src + i);
      float4 tv = *reinterpret_cast<const float4*>(temporal + (size_t)c * HWP + i);
      float4 o;
      o.x = a * cv.x + om * tv.x;
      o.y = a * cv.y + om * tv.y;
      o.z = a * cv.z + om * tv.z;
      o.w = a * cv.w + om * tv.w;
      *reinterpret_cast<float4*>(dyn + (size_t)c * HWP + i) = o;
    }
  }
}

// ================= bilateral 7x7, LDS tile [22][22][12] =================
#define TS 16
#define HALO 3
#define TL (TS + 2 * HALO)   // 22
#define NCH 12

__global__ __launch_bounds__(256) void bilateral_kernel(const float* __restrict__ dyn,
                                                        const float* __restrict__ feat,
                                                        const float* __restrict__ scale,
                                                        float* __restrict__ outdyn) {
  __shared__ float tile[TL * TL * NCH];
  constexpr int NBX = WW / TS;  // 80
  int bx = blockIdx.x % NBX;
  int by = blockIdx.x / NBX;
  int tx = threadIdx.x % TS;
  int ty = threadIdx.x / TS;

  for (int idx = threadIdx.x; idx < NCH * TL * TL; idx += 256) {
    int c = idx / (TL * TL);
    int rem = idx - c * (TL * TL);
    int ly = rem / TL;
    int lx = rem - ly * TL;
    int gy = min(max(by * TS + ly - HALO, 0), HH - 1);
    int gx = min(max(bx * TS + lx - HALO, 0), WW - 1);
    float v = (c < 4) ? dyn[c * HWP + gy * WW + gx]
                      : feat[(c - 4) * HWP + gy * WW + gx];
    tile[(ly * TL + lx) * NCH + c] = v;
  }
  __syncthreads();

  float s[8];
  #pragma unroll
  for (int c = 0; c < 8; ++c) s[c] = scale[c];

  const float* center = &tile[((ty + HALO) * TL + (tx + HALO)) * NCH];
  float fc[8];
  #pragma unroll
  for (int c = 0; c < 8; ++c) fc[c] = center[4 + c];

  float acc0 = 0.f, acc1 = 0.f, acc2 = 0.f, acc3 = 0.f, wsum = 0.f;
  #pragma unroll
  for (int dy = 0; dy < 7; ++dy) {
    #pragma unroll
    for (int dx = 0; dx < 7; ++dx) {
      const float* q = &tile[((ty + dy) * TL + (tx + dx)) * NCH];
      float4 f0 = *reinterpret_cast<const float4*>(q + 4);
      float4 f1 = *reinterpret_cast<const float4*>(q + 8);
      float e = 0.f;
      float d;
      d = fc[0] - f0.x; e = fmaf(s[0] * d, d, e);
      d = fc[1] - f0.y; e = fmaf(s[1] * d, d, e);
      d = fc[2] - f0.z; e = fmaf(s[2] * d, d, e);
      d = fc[3] - f0.w; e = fmaf(s[3] * d, d, e);
      d = fc[4] - f1.x; e = fmaf(s[4] * d, d, e);
      d = fc[5] - f1.y; e = fmaf(s[5] * d, d, e);
      d = fc[6] - f1.z; e = fmaf(s[6] * d, d, e);
      d = fc[7] - f1.w; e = fmaf(s[7] * d, d, e);
      float wgt = __expf(-e);
      float4 dv = *reinterpret_cast<const float4*>(q);
      acc0 = fmaf(wgt, dv.x, acc0);
      acc1 = fmaf(wgt, dv.y, acc1);
      acc2 = fmaf(wgt, dv.z, acc2);
      acc3 = fmaf(wgt, dv.w, acc3);
      wsum += wgt;
    }
  }
  int gy = by * TS + ty, gx = bx * TS + tx;
  int p = gy * WW + gx;
  float inv = 1.f / (wsum + 1e-8f);
  outdyn[0 * HWP + p] = acc0 * inv;
  outdyn[1 * HWP + p] = acc1 * inv;
  outdyn[2 * HWP + p] = acc2 * inv;
  outdyn[3 * HWP + p] = acc3 * inv;
}

// ================= output: albedo * dyn[0..2], float4 =================
__global__ __launch_bounds__(256) void out_v2(const float* __restrict__ albedo,
                                              const float* __restrict__ dyn,
                                              float* __restrict__ out) {
  int i = (blockIdx.x * 256 + threadIdx.x) * 4;
  if (i >= HWP) return;
  #pragma unroll
  for (int c = 0; c < 3; ++c) {
    float4 a = *reinterpret_cast<const float4*>(albedo + (size_t)c * HWP + i);
    float4 d = *reinterpret_cast<const float4*>(dyn + (size_t)c * HWP + i);
    float4 o;
    o.x = a.x * d.x; o.y = a.y * d.y; o.z = a.z * d.z; o.w = a.w * d.w;
    *reinterpret_cast<float4*>(out + (size_t)c * HWP + i) = o;
  }
}

extern "C" void kernel_launch(void* const* d_in, const int* in_sizes, int n_in,
                              void* d_out, int out_size, void* d_ws, size_t ws_size,
                              hipStream_t stream) {
  const float* x          = (const float*)d_in[0];
  const float* alpha      = (const float*)d_in[1];
  const float* cr_w0      = (const float*)d_in[2];
  const float* cr_b0      = (const float*)d_in[3];
  const float* cr_w1      = (const float*)d_in[4];
  const float* cr_b1      = (const float*)d_in[5];
  const float* cr_w2      = (const float*)d_in[6];
  const float* cr_b2      = (const float*)d_in[7];
  const float* hs_w0      = (const float*)d_in[8];
  const float* hs_b0      = (const float*)d_in[9];
  const float* hs_w1      = (const float*)d_in[10];
  const float* hs_b1      = (const float*)d_in[11];
  const float* hs_w2      = (const float*)d_in[12];
  const float* hs_b2      = (const float*)d_in[13];
  const float* filt_w     = (const float*)d_in[14];
  const float* filt_b     = (const float*)d_in[15];
  const float* filt_scale = (const float*)d_in[16];

  float* out  = (float*)d_out;
  float* ws   = (float*)d_ws;
  float* buf0 = ws;               // 12 planes
  float* buf1 = ws + 12 * (size_t)HWP;    // 12 planes
  float* dynA = ws + 24 * (size_t)HWP;    // 4 planes
  float* dynB = ws + 28 * (size_t)HWP;    // 4 planes
  float* feat = buf0;             // 8 planes, aliases buf0 (free during filter loop)

  const int NBC = (WW / 128) * (HH / 8);   // 900 blocks for conv/lcn tiles
  const int NBE = HWP / (256 * 4);         // 900 blocks for elementwise
  const int NBB = HWP / 256;               // 3600 blocks for bilateral (16x16 tiles... kept)
  dim3 blkC(128), blkE(256);

  for (int i = 0; i < NFRM; ++i) {
    const float* frame  = x + (size_t)i * 12 * HWP;
    const float* color  = frame;
    const float* fixedp = frame + 3 * (size_t)HWP;  // 9 planes (albedo at 0..2)
    const float* albedo = frame + 3 * (size_t)HWP;

    lcn_v2<<<NBC, blkC, 0, stream>>>(color, buf0);
    conv3x3_v2<6, 0, 6, true><<<NBC, blkC, 0, stream>>>(buf0, nullptr, cr_w0, cr_b0, buf1);
    conv3x3_v2<6, 0, 12, true><<<NBC, blkC, 0, stream>>>(buf1, nullptr, cr_w1, cr_b1, buf0);
    conv3x3_v2<12, 0, 3, false><<<NBC, blkC, 0, stream>>>(buf0, nullptr, cr_w2, cr_b2, buf1);
    conv3x3_v2<3, 9, 12, true><<<NBC, blkC, 0, stream>>>(buf1, fixedp, hs_w0, hs_b0, buf0);
    conv3x3_v2<12, 0, 12, true><<<NBC, blkC, 0, stream>>>(buf0, nullptr, hs_w1, hs_b1, buf1);
    conv3x3_v2<12, 0, 1, false><<<NBC, blkC, 0, stream>>>(buf1, nullptr, hs_w2, hs_b2, dynA + 3 * (size_t)HWP);
    blend_v2<<<NBE, blkE, 0, stream>>>(color, dynB, alpha, dynA, i == 0 ? 1 : 0);

    float* cur = dynA;
    float* nxt = dynB;
    for (int k = 0; k < 5; ++k) {
      conv3x3_v2<4, 9, 8, false><<<NBC, blkC, 0, stream>>>(cur, fixedp,
                                                           filt_w + (size_t)k * 8 * 13 * 9,
                                                           filt_b + k * 8, feat);
      bilateral_kernel<<<NBB, dim3(256), 0, stream>>>(cur, feat, filt_scale + k * 8, nxt);
      float* t = cur; cur = nxt; nxt = t;
    }
    // cur == dynB: temporal state for next frame
    out_v2<<<NBE, blkE, 0, stream>>>(albedo, cur, out + (size_t)i * 3 * HWP);
  }
}